// Round 4
// baseline (274.370 us; speedup 1.0000x reference)
//
#include <hip/hip_runtime.h>
#include <stddef.h>

#define CCH 128   // channels
#define VT  32    // vertices per gemm block

// ---------------- prep: A_t[c][o] = W1[o][c]-W2[o][c], W2_t[c][o] = W2[o][c]
__global__ void prep_weights(const float* __restrict__ w,
                             float* __restrict__ A_t, float* __restrict__ W2_t) {
    int i = blockIdx.x * 256 + threadIdx.x;    // i = c*128 + o, 16384 total
    int c = i >> 7, o = i & 127;
    float w2 = w[o * 256 + 128 + c];
    A_t[i]  = w[o * 256 + c] - w2;
    W2_t[i] = w2;
}

// ---------------- transpose x [128][N] -> x_t [N][128]
__global__ __launch_bounds__(256) void transpose_x(const float* __restrict__ x,
                                                   float* __restrict__ x_t, int N) {
    __shared__ float tile[32][33];
    int n0 = blockIdx.x * 32, c0 = blockIdx.y * 32;
    int tid = threadIdx.x;
    {
        int tx = tid & 31, r = tid >> 5;
        #pragma unroll
        for (int k = 0; k < 4; ++k) {
            int c = k * 8 + r;
            int n = n0 + tx;
            tile[c][tx] = (n < N) ? x[(size_t)(c0 + c) * N + n] : 0.f;
        }
    }
    __syncthreads();
    {
        int n = tid >> 3, cq = (tid & 7) * 4;
        if (n0 + n < N) {
            float4 v = make_float4(tile[cq][n], tile[cq + 1][n],
                                   tile[cq + 2][n], tile[cq + 3][n]);
            *(float4*)(x_t + (size_t)(n0 + n) * CCH + c0 + cq) = v;
        }
    }
}

// ---------------- CSR build: histogram
__global__ void hist_kernel(const int* __restrict__ ridx, int* __restrict__ counts, int E) {
    int e = blockIdx.x * 256 + threadIdx.x;
    if (e < E) atomicAdd(&counts[ridx[e]], 1);
}

// ---------------- CSR build: offsets via wave scan + one atomic per wave
__global__ void make_offsets(const int* __restrict__ counts, int* __restrict__ offs,
                             int* __restrict__ total, int N) {
    int n = blockIdx.x * 256 + threadIdx.x;
    int lane = threadIdx.x & 63;
    int c = (n < N) ? counts[n] : 0;
    int s = c;                                  // inclusive wave scan
    #pragma unroll
    for (int d = 1; d < 64; d <<= 1) {
        int u = __shfl_up(s, d);
        if (lane >= d) s += u;
    }
    int base = 0;
    if (lane == 63) base = atomicAdd(total, s);
    base = __shfl(base, 63);
    if (n < N) offs[n] = base + s - c;          // exclusive start (becomes cursor)
}

// ---------------- CSR build: fill edge lists (offs doubles as cursor -> end)
__global__ void fill_csr(const int* __restrict__ ridx, const int* __restrict__ gidx,
                         int* __restrict__ offs, int* __restrict__ csr, int E) {
    int e = blockIdx.x * 256 + threadIdx.x;
    if (e >= E) return;
    int p = atomicAdd(&offs[ridx[e]], 1);
    csr[p] = gidx[e];
}

// ---------------- gather-mean: one wave per vertex (2 per wave-iter), no LDS
__global__ __launch_bounds__(256) void gather_mean(
        const float4* __restrict__ xt4,     // x_t as [N][32] float4
        const int*   __restrict__ offs_end, // [N] (end after fill)
        const int*   __restrict__ counts,   // [N]
        const int*   __restrict__ csr,      // [E]
        float4*      __restrict__ gmean4,   // [N][32] float4
        int N) {
    int wave = threadIdx.x >> 6;
    int l = threadIdx.x & 63;
    int lq = l & 31;          // channel quad
    int half = l >> 5;        // edge-pair half
    #pragma unroll
    for (int i = 0; i < 2; ++i) {
        int n = blockIdx.x * 8 + wave * 2 + i;
        if (n >= N) break;    // uniform per wave
        int end = __builtin_amdgcn_readfirstlane(offs_end[n]);
        int deg = __builtin_amdgcn_readfirstlane(counts[n]);
        int off = end - deg;
        float4 acc = make_float4(0.f, 0.f, 0.f, 0.f);
        int k = 0;
        for (; k + 8 <= deg; k += 8) {          // 4 outstanding 16B gathers/lane
            int g0 = csr[off + k +     half];
            int g1 = csr[off + k + 2 + half];
            int g2 = csr[off + k + 4 + half];
            int g3 = csr[off + k + 6 + half];
            float4 a = xt4[(size_t)g0 * 32 + lq];
            float4 b = xt4[(size_t)g1 * 32 + lq];
            float4 c2 = xt4[(size_t)g2 * 32 + lq];
            float4 d2 = xt4[(size_t)g3 * 32 + lq];
            acc.x += (a.x + b.x) + (c2.x + d2.x);
            acc.y += (a.y + b.y) + (c2.y + d2.y);
            acc.z += (a.z + b.z) + (c2.z + d2.z);
            acc.w += (a.w + b.w) + (c2.w + d2.w);
        }
        for (; k + 2 <= deg; k += 2) {
            int g = csr[off + k + half];
            float4 a = xt4[(size_t)g * 32 + lq];
            acc.x += a.x; acc.y += a.y; acc.z += a.z; acc.w += a.w;
        }
        if (k < deg && half == 0) {
            int g = csr[off + k];
            float4 a = xt4[(size_t)g * 32 + lq];
            acc.x += a.x; acc.y += a.y; acc.z += a.z; acc.w += a.w;
        }
        acc.x += __shfl_xor(acc.x, 32);
        acc.y += __shfl_xor(acc.y, 32);
        acc.z += __shfl_xor(acc.z, 32);
        acc.w += __shfl_xor(acc.w, 32);
        float inv = (deg > 0) ? 1.f / (float)deg : 0.f;
        if (half == 0)
            gmean4[(size_t)n * 32 + lq] =
                make_float4(acc.x * inv, acc.y * inv, acc.z * inv, acc.w * inv);
    }
}

// ---------------- gemm: out = mask * leaky(A@x + W2@gmean + bias)
__global__ __launch_bounds__(256) void gemm_out(
        const float*  __restrict__ x,       // [128][N]
        const float4* __restrict__ gmean4,  // [N][32] float4
        const int*    __restrict__ counts,  // [N]
        const float4* __restrict__ A_t4,    // [c][o] 128x128 as float4
        const float4* __restrict__ W2_t4,   // [c][o] 128x128 as float4
        const float*  __restrict__ bias,    // [128]
        float* __restrict__ out,            // [128][N]
        int N) {
    __shared__ float xt[CCH][VT];     // 16 KB
    __shared__ float gt[VT][CCH];     // 16 KB
    __shared__ float wA[16][CCH];     // 8 KB
    __shared__ float wB[16][CCH];     // 8 KB
    int n0 = blockIdx.x * VT;
    int t = threadIdx.x;

    // stage x[c][n0..n0+31] -> xt[c][v]
    #pragma unroll
    for (int k = 0; k < 4; ++k) {
        int idx = k * 256 + t;
        int c = idx >> 3;
        int f4 = (idx & 7) * 4;
        float4 val = make_float4(0.f, 0.f, 0.f, 0.f);
        if (n0 + f4 < N)               // N%4==0
            val = *(const float4*)(x + (size_t)c * N + n0 + f4);
        *(float4*)&xt[c][f4] = val;
    }
    // stage gmean[n0+v][:] -> gt[v][c]  (coalesced float4 both sides)
    #pragma unroll
    for (int k = 0; k < 4; ++k) {
        int idx = k * 256 + t;
        int v = idx >> 5;
        int c4 = idx & 31;
        float4 g = make_float4(0.f, 0.f, 0.f, 0.f);
        if (n0 + v < N) g = gmean4[(size_t)(n0 + v) * 32 + c4];
        *(float4*)&gt[v][c4 * 4] = g;
    }

    int l = t & 31;     // o quad
    int w = t >> 5;     // vertex quad 0..7
    float acc[4][4];
    #pragma unroll
    for (int i = 0; i < 4; ++i)
        #pragma unroll
        for (int j = 0; j < 4; ++j) acc[i][j] = 0.f;

    for (int ct = 0; ct < 8; ++ct) {
        __syncthreads();   // previous tile consumed (first iter: covers xt/gt too)
        // stage 16 rows of A_t / W2_t into LDS
        #pragma unroll
        for (int k = 0; k < 2; ++k) {
            int idx = k * 256 + t;
            int r = idx >> 5;
            int c4 = idx & 31;
            *(float4*)&wA[r][c4 * 4] = A_t4[(size_t)(ct * 16 + r) * 32 + c4];
            *(float4*)&wB[r][c4 * 4] = W2_t4[(size_t)(ct * 16 + r) * 32 + c4];
        }
        __syncthreads();
        #pragma unroll
        for (int cc = 0; cc < 16; ++cc) {
            int c = ct * 16 + cc;
            float4 a = *(const float4*)&wA[cc][4 * l];
            float4 b = *(const float4*)&wB[cc][4 * l];
            float4 xv = *(const float4*)&xt[c][4 * w];
            const float* ap = (const float*)&a;
            const float* bp = (const float*)&b;
            const float* xp = (const float*)&xv;
            float gp[4];
            #pragma unroll
            for (int j = 0; j < 4; ++j) gp[j] = gt[4 * w + j][c];
            #pragma unroll
            for (int i = 0; i < 4; ++i)
                #pragma unroll
                for (int j = 0; j < 4; ++j)
                    acc[i][j] += ap[i] * xp[j] + bp[i] * gp[j];
        }
    }

    int vbase = n0 + 4 * w;
    if (vbase < N) {                 // N%4==0
        float4 bi = *(const float4*)(bias + 4 * l);
        const float* bp = (const float*)&bi;
        float m[4];
        #pragma unroll
        for (int j = 0; j < 4; ++j)
            m[j] = (counts[vbase + j] > 0) ? 1.f : 0.f;
        #pragma unroll
        for (int i = 0; i < 4; ++i) {
            int o = 4 * l + i;
            float r[4];
            #pragma unroll
            for (int j = 0; j < 4; ++j) {
                float v = (acc[i][j] + bp[i]) * m[j];
                r[j] = (v >= 0.f) ? v : 0.3f * v;
            }
            *(float4*)(out + (size_t)o * N + vbase) = make_float4(r[0], r[1], r[2], r[3]);
        }
    }
}

// ---------------- fallback: fused gather+gemm (round-3 proven), offs=end variant
__global__ __launch_bounds__(256) void fused_out(
        const float* __restrict__ x,
        const float* __restrict__ x_t,
        const int*   __restrict__ offs_end,
        const int*   __restrict__ counts,
        const int*   __restrict__ csr,
        const float* __restrict__ A_t,
        const float* __restrict__ W2_t,
        const float* __restrict__ bias,
        float* __restrict__ out,
        int N) {
    __shared__ float xt[CCH][VT + 4];
    __shared__ float gt[VT][CCH];
    int n0 = blockIdx.x * VT;
    int tid = threadIdx.x;

    #pragma unroll
    for (int k = 0; k < 4; ++k) {
        int idx = k * 256 + tid;
        int c = idx >> 3;
        int f4 = (idx & 7) * 4;
        float4 val = make_float4(0.f, 0.f, 0.f, 0.f);
        if (n0 + f4 < N)
            val = *(const float4*)(x + (size_t)c * N + n0 + f4);
        *(float4*)&xt[c][f4] = val;
    }
    {
        int w = tid >> 6;
        int l = tid & 63;
        int lq = l & 31;
        int half = l >> 5;
        const float4* xt4 = (const float4*)x_t;
        for (int i = 0; i < 8; ++i) {
            int v = w * 8 + i;
            int n = n0 + v;
            float4 acc = make_float4(0.f, 0.f, 0.f, 0.f);
            int deg = 0;
            if (n < N) {
                int end = __builtin_amdgcn_readfirstlane(offs_end[n]);
                deg     = __builtin_amdgcn_readfirstlane(counts[n]);
                int off = end - deg;
                int k = 0;
                for (; k + 8 <= deg; k += 8) {
                    int g0 = csr[off + k +     half];
                    int g1 = csr[off + k + 2 + half];
                    int g2 = csr[off + k + 4 + half];
                    int g3 = csr[off + k + 6 + half];
                    float4 a = xt4[(size_t)g0 * 32 + lq];
                    float4 b = xt4[(size_t)g1 * 32 + lq];
                    float4 c2 = xt4[(size_t)g2 * 32 + lq];
                    float4 d2 = xt4[(size_t)g3 * 32 + lq];
                    acc.x += (a.x + b.x) + (c2.x + d2.x);
                    acc.y += (a.y + b.y) + (c2.y + d2.y);
                    acc.z += (a.z + b.z) + (c2.z + d2.z);
                    acc.w += (a.w + b.w) + (c2.w + d2.w);
                }
                for (; k + 2 <= deg; k += 2) {
                    int g = csr[off + k + half];
                    float4 a = xt4[(size_t)g * 32 + lq];
                    acc.x += a.x; acc.y += a.y; acc.z += a.z; acc.w += a.w;
                }
                if (k < deg && half == 0) {
                    int g = csr[off + k];
                    float4 a = xt4[(size_t)g * 32 + lq];
                    acc.x += a.x; acc.y += a.y; acc.z += a.z; acc.w += a.w;
                }
            }
            acc.x += __shfl_xor(acc.x, 32);
            acc.y += __shfl_xor(acc.y, 32);
            acc.z += __shfl_xor(acc.z, 32);
            acc.w += __shfl_xor(acc.w, 32);
            float inv = (deg > 0) ? 1.f / (float)deg : 0.f;
            if (half == 0) {
                float4 r = make_float4(acc.x * inv, acc.y * inv, acc.z * inv, acc.w * inv);
                *(float4*)&gt[v][4 * lq] = r;
            }
        }
    }
    __syncthreads();

    int l = tid & 31;
    int w = tid >> 5;
    float acc[4][4];
    #pragma unroll
    for (int i = 0; i < 4; ++i)
        #pragma unroll
        for (int j = 0; j < 4; ++j) acc[i][j] = 0.f;

    const float4* At4 = (const float4*)A_t;
    const float4* W24 = (const float4*)W2_t;
    for (int c = 0; c < CCH; ++c) {
        float4 a = At4[c * 32 + l];
        float4 b = W24[c * 32 + l];
        float4 xv = *(const float4*)&xt[c][4 * w];
        const float* ap = (const float*)&a;
        const float* bp = (const float*)&b;
        const float* xp = (const float*)&xv;
        float gp[4];
        #pragma unroll
        for (int j = 0; j < 4; ++j) gp[j] = gt[4 * w + j][c];
        #pragma unroll
        for (int i = 0; i < 4; ++i)
            #pragma unroll
            for (int j = 0; j < 4; ++j)
                acc[i][j] += ap[i] * xp[j] + bp[i] * gp[j];
    }

    int vbase = n0 + 4 * w;
    if (vbase < N) {
        float4 bi = *(const float4*)(bias + 4 * l);
        const float* bp = (const float*)&bi;
        float m[4];
        #pragma unroll
        for (int j = 0; j < 4; ++j)
            m[j] = (counts[vbase + j] > 0) ? 1.f : 0.f;
        #pragma unroll
        for (int i = 0; i < 4; ++i) {
            int o = 4 * l + i;
            float r[4];
            #pragma unroll
            for (int j = 0; j < 4; ++j) {
                float v = (acc[i][j] + bp[i]) * m[j];
                r[j] = (v >= 0.f) ? v : 0.3f * v;
            }
            *(float4*)(out + (size_t)o * N + vbase) = make_float4(r[0], r[1], r[2], r[3]);
        }
    }
}

extern "C" void kernel_launch(void* const* d_in, const int* in_sizes, int n_in,
                              void* d_out, int out_size, void* d_ws, size_t ws_size,
                              hipStream_t stream) {
    const float* x      = (const float*)d_in[0];  // [1,128,N]
    const float* weight = (const float*)d_in[1];  // [128,256]
    const float* bias   = (const float*)d_in[2];  // [128]
    const int*   ridx   = (const int*)d_in[3];    // [E]
    const int*   gidx   = (const int*)d_in[4];    // [E]
    float* out = (float*)d_out;

    int N = in_sizes[0] / CCH;   // 50000
    int E = in_sizes[3];         // 800000

    char* ws = (char*)d_ws;
    size_t xt_bytes = (size_t)N * CCH * sizeof(float);       // 25.6 MB
    size_t n_bytes  = ((size_t)N * sizeof(int) + 63) & ~63;  // aligned
    size_t csr_bytes = ((size_t)E * sizeof(int) + 63) & ~63;

    size_t o = 0;
    float* x_t    = (float*)(ws + o); o += xt_bytes;
    int*   counts = (int*)  (ws + o); o += n_bytes;
    int*   total  = (int*)  (ws + o); o += 64;
    int*   offs   = (int*)  (ws + o); o += n_bytes;
    int*   csr    = (int*)  (ws + o); o += csr_bytes;
    float* A_t    = (float*)(ws + o); o += CCH * CCH * sizeof(float);
    float* W2_t   = (float*)(ws + o); o += CCH * CCH * sizeof(float);
    float* gmean  = (float*)(ws + o);
    bool split = (ws_size >= o + xt_bytes);   // gmean fits?

    // zero counts + total (adjacent)
    hipMemsetAsync(counts, 0, n_bytes + 64, stream);

    prep_weights<<<(CCH * CCH) / 256, 256, 0, stream>>>(weight, A_t, W2_t);

    dim3 tg((N + 31) / 32, CCH / 32);
    transpose_x<<<tg, 256, 0, stream>>>(x, x_t, N);

    int eblocks = (E + 255) / 256;
    int nblocks = (N + 255) / 256;
    hist_kernel<<<eblocks, 256, 0, stream>>>(ridx, counts, E);
    make_offsets<<<nblocks, 256, 0, stream>>>(counts, offs, total, N);
    fill_csr<<<eblocks, 256, 0, stream>>>(ridx, gidx, offs, csr, E);
    // offs[n] is now segment END; start = end - counts[n]

    if (split) {
        gather_mean<<<(N + 7) / 8, 256, 0, stream>>>(
            (const float4*)x_t, offs, counts, csr, (float4*)gmean, N);
        gemm_out<<<(N + VT - 1) / VT, 256, 0, stream>>>(
            x, (const float4*)gmean, counts,
            (const float4*)A_t, (const float4*)W2_t, bias, out, N);
    } else {
        fused_out<<<(N + VT - 1) / VT, 256, 0, stream>>>(
            x, x_t, offs, counts, csr, A_t, W2_t, bias, out, N);
    }
}

// Round 5
// 217.166 us; speedup vs baseline: 1.2634x; 1.2634x over previous
//
#include <hip/hip_runtime.h>
#include <stddef.h>

#define CCH 128   // channels
#define VT  64    // vertices per gemm block

typedef unsigned int  uint;
typedef unsigned short ushort;

__device__ __forceinline__ ushort f2bf(float f) {        // RNE float->bf16
    uint b = __float_as_uint(f);
    b += 0x7FFFu + ((b >> 16) & 1u);
    return (ushort)(b >> 16);
}
__device__ __forceinline__ float bflo(uint u) { return __uint_as_float(u << 16); }
__device__ __forceinline__ float bfhi(uint u) { return __uint_as_float(u & 0xFFFF0000u); }

// ---------------- prep: A_t[c][o] = W1[o][c]-W2[o][c], W2_t[c][o] = W2[o][c]
//                  + zero counts/total (replaces memset launch)
__global__ void prep_zero(const float* __restrict__ w,
                          float* __restrict__ A_t, float* __restrict__ W2_t,
                          int* __restrict__ zero_buf, int NZ) {
    int i = blockIdx.x * 256 + threadIdx.x;
    if (i < CCH * CCH) {
        int c = i >> 7, o = i & 127;
        float w2 = w[o * 256 + 128 + c];
        A_t[i]  = w[o * 256 + c] - w2;
        W2_t[i] = w2;
    }
    for (int n = i; n < NZ; n += gridDim.x * 256) zero_buf[n] = 0;
}

// ---------------- transpose x [128][N] -> x_t bf16 [N][128], fused edge histogram
__global__ __launch_bounds__(256) void transpose_hist(
        const float* __restrict__ x, ushort* __restrict__ xtb,
        const int* __restrict__ ridx, int* __restrict__ counts, int N, int E) {
    __shared__ float tile[32][33];
    int n0 = blockIdx.x * 32, c0 = blockIdx.y * 32;
    int tid = threadIdx.x;
    {
        int tx = tid & 31, r = tid >> 5;
        #pragma unroll
        for (int k = 0; k < 4; ++k) {
            int c = k * 8 + r;
            int n = n0 + tx;
            tile[c][tx] = (n < N) ? x[(size_t)(c0 + c) * N + n] : 0.f;
        }
    }
    // fused histogram: this block handles a 128-edge slice (grid-stride)
    {
        int flatb = blockIdx.y * gridDim.x + blockIdx.x;
        int slots = gridDim.x * gridDim.y * 128;
        if (tid < 128)
            for (int e = flatb * 128 + tid; e < E; e += slots)
                atomicAdd(&counts[ridx[e]], 1);
    }
    __syncthreads();
    {
        int n = tid >> 3, c4 = (tid & 7) * 4;
        if (n0 + n < N) {
            ushort4 u;
            u.x = f2bf(tile[c4][n]);
            u.y = f2bf(tile[c4 + 1][n]);
            u.z = f2bf(tile[c4 + 2][n]);
            u.w = f2bf(tile[c4 + 3][n]);
            *(ushort4*)(xtb + (size_t)(n0 + n) * CCH + c0 + c4) = u;
        }
    }
}

// ---------------- CSR build: offsets via wave scan + one atomic per wave
__global__ void make_offsets(const int* __restrict__ counts, int* __restrict__ offs,
                             int* __restrict__ total, int N) {
    int n = blockIdx.x * 256 + threadIdx.x;
    int lane = threadIdx.x & 63;
    int c = (n < N) ? counts[n] : 0;
    int s = c;
    #pragma unroll
    for (int d = 1; d < 64; d <<= 1) {
        int u = __shfl_up(s, d);
        if (lane >= d) s += u;
    }
    int base = 0;
    if (lane == 63) base = atomicAdd(total, s);
    base = __shfl(base, 63);
    if (n < N) offs[n] = base + s - c;          // exclusive start (becomes cursor)
}

// ---------------- CSR build: fill edge lists (offs doubles as cursor -> end)
__global__ void fill_csr(const int* __restrict__ ridx, const int* __restrict__ gidx,
                         int* __restrict__ offs, int* __restrict__ csr, int E) {
    int e = blockIdx.x * 256 + threadIdx.x;
    if (e >= E) return;
    int p = atomicAdd(&offs[ridx[e]], 1);
    csr[p] = gidx[e];
}

// ---------------- gather-mean over bf16 x_t: one wave per vertex, no LDS
__global__ __launch_bounds__(256) void gather_mean(
        const uint2* __restrict__ xtb,      // [N][32] uint2 = bf16x4 quads
        const int*   __restrict__ offs_end, // [N] (end after fill)
        const int*   __restrict__ counts,   // [N]
        const int*   __restrict__ csr,      // [E]
        float4*      __restrict__ gmean4,   // [N][32] float4
        int N) {
    int wave = threadIdx.x >> 6;
    int l = threadIdx.x & 63;
    int lq = l & 31;          // channel quad
    int half = l >> 5;        // edge-pair half
    #pragma unroll
    for (int i = 0; i < 2; ++i) {
        int n = blockIdx.x * 8 + wave * 2 + i;
        if (n >= N) return;   // wave-uniform
        int end = __builtin_amdgcn_readfirstlane(offs_end[n]);
        int deg = __builtin_amdgcn_readfirstlane(counts[n]);
        int off = end - deg;
        float4 acc = make_float4(0.f, 0.f, 0.f, 0.f);
        int k = 0;
        for (; k + 16 <= deg; k += 16) {        // 8 outstanding 8B gathers/lane
            uint2 u[8];
            #pragma unroll
            for (int q = 0; q < 8; ++q) {
                int g = csr[off + k + 2 * q + half];
                u[q] = xtb[(size_t)g * 32 + lq];
            }
            #pragma unroll
            for (int q = 0; q < 8; ++q) {
                acc.x += bflo(u[q].x); acc.y += bfhi(u[q].x);
                acc.z += bflo(u[q].y); acc.w += bfhi(u[q].y);
            }
        }
        for (; k + 8 <= deg; k += 8) {
            uint2 u[4];
            #pragma unroll
            for (int q = 0; q < 4; ++q) {
                int g = csr[off + k + 2 * q + half];
                u[q] = xtb[(size_t)g * 32 + lq];
            }
            #pragma unroll
            for (int q = 0; q < 4; ++q) {
                acc.x += bflo(u[q].x); acc.y += bfhi(u[q].x);
                acc.z += bflo(u[q].y); acc.w += bfhi(u[q].y);
            }
        }
        for (; k + 2 <= deg; k += 2) {
            int g = csr[off + k + half];
            uint2 u = xtb[(size_t)g * 32 + lq];
            acc.x += bflo(u.x); acc.y += bfhi(u.x);
            acc.z += bflo(u.y); acc.w += bfhi(u.y);
        }
        if (k < deg && half == 0) {
            int g = csr[off + k];
            uint2 u = xtb[(size_t)g * 32 + lq];
            acc.x += bflo(u.x); acc.y += bfhi(u.x);
            acc.z += bflo(u.y); acc.w += bfhi(u.y);
        }
        acc.x += __shfl_xor(acc.x, 32);
        acc.y += __shfl_xor(acc.y, 32);
        acc.z += __shfl_xor(acc.z, 32);
        acc.w += __shfl_xor(acc.w, 32);
        float inv = (deg > 0) ? 1.f / (float)deg : 0.f;
        if (half == 0)
            gmean4[(size_t)n * 32 + lq] =
                make_float4(acc.x * inv, acc.y * inv, acc.z * inv, acc.w * inv);
    }
}

// ---------------- gemm: out = mask * leaky(A@x + W2@gmean + bias)
// one barrier; x + weights stream from L1/L2; only gmean tile in LDS
__global__ __launch_bounds__(256) void gemm_out(
        const float*  __restrict__ x,       // [128][N]
        const float4* __restrict__ gmean4,  // [N][32] float4
        const int*    __restrict__ counts,  // [N]
        const float4* __restrict__ A_t4,    // [c][o] 128x128 as float4
        const float4* __restrict__ W2_t4,   // [c][o] 128x128 as float4
        const float*  __restrict__ bias,    // [128]
        float* __restrict__ out,            // [128][N]
        int N) {
    __shared__ float gt[VT][CCH];           // 32 KB
    int n0 = blockIdx.x * VT;
    int t = threadIdx.x;

    // stage gmean[n0+v][:] -> gt[v][c]  (coalesced float4 both sides, 4-way bank ok)
    #pragma unroll
    for (int k = 0; k < 8; ++k) {
        int idx = k * 256 + t;
        int v = idx >> 5;
        int c4 = idx & 31;
        float4 g = make_float4(0.f, 0.f, 0.f, 0.f);
        if (n0 + v < N) g = gmean4[(size_t)(n0 + v) * 32 + c4];
        *(float4*)&gt[v][c4 * 4] = g;
    }
    __syncthreads();

    int l = t & 31;        // o quad: o = 4l..4l+3
    int w = t >> 5;        // vertex oct: v = 8w..8w+7
    int vb = n0 + 8 * w;
    int sb = (vb + 8 <= N) ? vb : ((N >= 8) ? N - 8 : 0);   // safe (aligned) x base
    float acc[4][8];
    #pragma unroll
    for (int i = 0; i < 4; ++i)
        #pragma unroll
        for (int j = 0; j < 8; ++j) acc[i][j] = 0.f;

    #pragma unroll 2
    for (int c = 0; c < CCH; ++c) {
        float4 a = A_t4[c * 32 + l];
        float4 b = W2_t4[c * 32 + l];
        float4 x0 = *(const float4*)(x + (size_t)c * N + sb);
        float4 x1 = *(const float4*)(x + (size_t)c * N + sb + 4);
        float gp[8];
        #pragma unroll
        for (int j = 0; j < 8; ++j) gp[j] = gt[8 * w + j][c];   // LDS broadcast
        const float* ap = (const float*)&a;
        const float* bp = (const float*)&b;
        const float* xp = (const float*)&x0;
        const float* xq = (const float*)&x1;
        #pragma unroll
        for (int i = 0; i < 4; ++i) {
            #pragma unroll
            for (int j = 0; j < 4; ++j) {
                acc[i][j]     += ap[i] * xp[j] + bp[i] * gp[j];
                acc[i][j + 4] += ap[i] * xq[j] + bp[i] * gp[j + 4];
            }
        }
    }

    // epilogue: + bias, empty-segment mask, leaky relu, float4 stores
    if (vb < N) {                     // N%8==0 -> all 8 valid
        float4 bi = *(const float4*)(bias + 4 * l);
        const float* bp = (const float*)&bi;
        float m[8];
        #pragma unroll
        for (int j = 0; j < 8; ++j) m[j] = (counts[vb + j] > 0) ? 1.f : 0.f;
        #pragma unroll
        for (int i = 0; i < 4; ++i) {
            int o = 4 * l + i;
            float r[8];
            #pragma unroll
            for (int j = 0; j < 8; ++j) {
                float v = (acc[i][j] + bp[i]) * m[j];
                r[j] = (v >= 0.f) ? v : 0.3f * v;
            }
            *(float4*)(out + (size_t)o * N + vb)     = make_float4(r[0], r[1], r[2], r[3]);
            *(float4*)(out + (size_t)o * N + vb + 4) = make_float4(r[4], r[5], r[6], r[7]);
        }
    }
}

extern "C" void kernel_launch(void* const* d_in, const int* in_sizes, int n_in,
                              void* d_out, int out_size, void* d_ws, size_t ws_size,
                              hipStream_t stream) {
    const float* x      = (const float*)d_in[0];  // [1,128,N]
    const float* weight = (const float*)d_in[1];  // [128,256]
    const float* bias   = (const float*)d_in[2];  // [128]
    const int*   ridx   = (const int*)d_in[3];    // [E]
    const int*   gidx   = (const int*)d_in[4];    // [E]
    float* out = (float*)d_out;

    int N = in_sizes[0] / CCH;   // 50000
    int E = in_sizes[3];         // 800000

    char* ws = (char*)d_ws;
    size_t xtb_bytes = (((size_t)N * CCH * sizeof(ushort)) + 63) & ~(size_t)63;
    size_t n_bytes   = (((size_t)N * sizeof(int)) + 63) & ~(size_t)63;
    size_t csr_bytes = (((size_t)E * sizeof(int)) + 63) & ~(size_t)63;
    size_t w_bytes   = (size_t)CCH * CCH * sizeof(float);

    size_t o = 0;
    ushort* xtb   = (ushort*)(ws + o); o += xtb_bytes;
    int*    counts= (int*)   (ws + o); o += n_bytes;
    int*    total = (int*)   (ws + o); o += 64;
    int*    offs  = (int*)   (ws + o); o += n_bytes;
    int*    csr   = (int*)   (ws + o); o += csr_bytes;
    float*  A_t   = (float*) (ws + o); o += w_bytes;
    float*  W2_t  = (float*) (ws + o); o += w_bytes;
    float*  gmean = (float*) (ws + o);

    // 1. weights prep + zero counts/total
    prep_zero<<<196, 256, 0, stream>>>(weight, A_t, W2_t, counts, N + 16);

    // 2. transpose to bf16 + fused histogram
    dim3 tg((N + 31) / 32, CCH / 32);
    transpose_hist<<<tg, 256, 0, stream>>>(x, xtb, ridx, counts, N, E);

    // 3-4. offsets + CSR fill
    int eblocks = (E + 255) / 256;
    int nblocks = (N + 255) / 256;
    make_offsets<<<nblocks, 256, 0, stream>>>(counts, offs, total, N);
    fill_csr<<<eblocks, 256, 0, stream>>>(ridx, gidx, offs, csr, E);
    // offs[n] is now segment END; start = end - counts[n]

    // 5. gather-mean (bf16 reads, fp32 accumulate)
    gather_mean<<<(N + 7) / 8, 256, 0, stream>>>(
        (const uint2*)xtb, offs, counts, csr, (float4*)gmean, N);

    // 6. dual GEMM + bias + mask + leaky
    gemm_out<<<(N + VT - 1) / VT, 256, 0, stream>>>(
        x, (const float4*)gmean, counts,
        (const float4*)A_t, (const float4*)W2_t, bias, out, N);
}